// Round 15
// baseline (43.232 us; speedup 1.0000x reference)
//
#include <hip/hip_runtime.h>
#include <hip/hip_bf16.h>
#include <math.h>

// Problem constants
#define Bn 8
#define Cn 64
#define Hn 128
#define Wn 128
#define Rn 4

typedef __bf16 v8bf __attribute__((ext_vector_type(8)));
typedef float  v16f __attribute__((ext_vector_type(16)));

__device__ __forceinline__ float leaky(float x) { return x >= 0.f ? x : 0.1f * x; }

__device__ __forceinline__ unsigned bf16pair(float a, float b) {
    __hip_bfloat16 ha = __float2bfloat16(a);
    __hip_bfloat16 hb = __float2bfloat16(b);
    return (unsigned)*reinterpret_cast<unsigned short*>(&ha) |
           ((unsigned)*reinterpret_cast<unsigned short*>(&hb) << 16);
}

// ---------------------------------------------------------------------------
// Kernel A: per-batch dynamic depthwise kernels + channel attn; block Bn
// converts w_conv -> bf16 [o][c].
//   kern_g[b][c][r][12] row-major taps (kk = row*3+col; slots 9..11 pad)
//   att_g [b][r][c]
// ---------------------------------------------------------------------------
__global__ __launch_bounds__(256) void precomp_kernel(
    const float* __restrict__ deg, const float* __restrict__ w_k1,
    const float* __restrict__ w_k2, const float* __restrict__ w_ca1,
    const float* __restrict__ w_ca2, const float* __restrict__ w_conv,
    float* __restrict__ kern_g, float* __restrict__ att_g,
    unsigned short* __restrict__ wbf)
{
    const int tid = threadIdx.x;
    if (blockIdx.x == Bn) {                       // w_conv -> bf16
        for (int f = tid; f < Cn * Cn; f += 256) {
            __hip_bfloat16 hx = __float2bfloat16(w_conv[f]);
            wbf[f] = *reinterpret_cast<unsigned short*>(&hx);
        }
        return;
    }
    const int b = blockIdx.x;
    __shared__ float y_s[64], a_s[64];
    if (tid < 64) {
        float sy = 0.f, sa = 0.f;
#pragma unroll 8
        for (int j = 0; j < 64; ++j) {
            float d = deg[b * 64 + j];
            sy += d * w_k1[tid * 64 + j];
            sa += d * w_ca1[tid * 64 + j];
        }
        y_s[tid] = leaky(sy);
        a_s[tid] = leaky(sa);
    }
    __syncthreads();
    for (int f = tid; f < Cn * Rn * 9; f += 256) {
        int c = f / 36;
        int j = f - c * 36;
        int r = j / 9;
        int kk = j - r * 9;
        int o = c * 9 + kk;
        const float* wp = &w_k2[(r * 576 + o) * 16];
        const float* yp = &y_s[r * 16];
        float s = 0.f;
#pragma unroll
        for (int i = 0; i < 16; ++i) s += yp[i] * wp[i];
        kern_g[b * 3072 + c * 48 + r * 12 + kk] = s;
    }
    {
        int r = tid >> 6, o = tid & 63;
        const float* wp = &w_ca2[(r * 64 + o) * 16];
        const float* ap = &a_s[r * 16];
        float s = 0.f;
#pragma unroll
        for (int i = 0; i < 16; ++i) s += ap[i] * wp[i];
        att_g[b * 256 + tid] = 1.f / (1.f + expf(-s));
    }
}

// ---------------------------------------------------------------------------
// Main kernel: one block per (b,h) row, 512 threads = 8 waves, 2 barriers.
// Phase 1 is LDS-minimal: per channel 9 DIRECT VMEM tap loads (w+-1 are L1
// hits; borders masked with cndmask -- no shuffles, no edge special cases),
// 3 LDS kern reads (gather form), 1-channel-ahead prefetch. Results packed
// to bf16 and written with 2 conflict-free ds_write_b128/thread into the
// subtiled t_lds[cq][w][8] (R8/R13-verified layout).
// Phase 2: R10/R13-verified MFMA path + fused epilogue.
// ---------------------------------------------------------------------------
__global__ __launch_bounds__(512) void da_main(
    const float* __restrict__ x0, const float* __restrict__ q_map,
    const unsigned short* __restrict__ wbf, const float* __restrict__ b_conv,
    const float* __restrict__ w_g1, const float* __restrict__ b_g1,
    const float* __restrict__ w_g2, const float* __restrict__ b_g2,
    const float* __restrict__ kern_g, const float* __restrict__ att_g,
    float* __restrict__ out)
{
    __shared__ __align__(16) float kern_lds[Cn * 48];           // 12 KB
    __shared__ __align__(16) unsigned short wc_lds[8][Cn][8];   // 8 KB
    __shared__ __align__(16) unsigned short t_lds[8][Wn][8];    // 16 KB (subtiled)
    __shared__ float att_lds[Rn * 68];                          // 1.1 KB
    __shared__ float bias_lds[Cn];                              // 0.25 KB
    __shared__ unsigned ridx[Wn];                               // 0.5 KB  r1 | r2<<16

    const int tid = threadIdx.x;
    const int ob = blockIdx.x;
    // XCD-aware swizzle: XCD i gets batch i (4 MB image == one L2).
    const int sb = ((ob & 7) << 7) | (ob >> 3);
    const int b = sb >> 7;
    const int h = sb & 127;

    const int w = tid & 127;
    const int q = tid >> 7;               // channel quarter: [16q, 16q+16)

    // ---- phase 0: staging ----
    for (int f = tid; f < Cn * 48; f += 512)
        kern_lds[f] = kern_g[b * 3072 + f];
    {   // wc subtiles: one conflict-free b128 write per thread
        int cq = tid & 7, o = tid >> 3;
        *(v8bf*)&wc_lds[cq][o][0] = *(const v8bf*)&wbf[o * 64 + cq * 8];
    }
    if (tid < 256) att_lds[(tid >> 6) * 68 + (tid & 63)] = att_g[b * 256 + tid];
    if (tid < 64) bias_lds[tid] = b_conv[tid];

    // routing: once per column, published packed (r1 | r2<<16)
    if (tid < 128) {
        const int wc = tid;
        float qv[9];
#pragma unroll
        for (int dh = 0; dh < 3; ++dh) {
            int row = h - 1 + dh;
#pragma unroll
            for (int dw = 0; dw < 3; ++dw) {
                int col = wc - 1 + dw;
                qv[dh * 3 + dw] = (row >= 0 && row < Hn && col >= 0 && col < Wn)
                                      ? q_map[(b * Hn + row) * Wn + col] : 0.f;
            }
        }
        float best1 = -1e30f, best2 = -1e30f;
        int r1 = 0, r2 = 0;
#pragma unroll
        for (int r = 0; r < Rn; ++r) {
            float s1 = b_g1[r], s2 = b_g2[r];
#pragma unroll
            for (int k = 0; k < 9; ++k) {
                s1 += qv[k] * w_g1[r * 9 + k];
                s2 += qv[k] * w_g2[r * 9 + k];
            }
            if (s1 > best1) { best1 = s1; r1 = r; }   // strict > == first argmax
            if (s2 > best2) { best2 = s2; r2 = r; }
        }
        ridx[wc] = (unsigned)r1 | ((unsigned)r2 << 16);
    }
    __syncthreads();

    // ---- phase 1: depthwise conv, 16 channels/thread, LDS-minimal ----
    const bool okm = (h > 0);
    const bool okp = (h < Hn - 1);
    const bool mL = (w > 0);
    const bool mR = (w < Wn - 1);
    const int wl = mL ? -1 : 0;           // clamped offsets (values masked)
    const int wr_ = mR ? 1 : 0;
    const float* xbase = x0 + (size_t)(b * Cn) * Hn * Wn + h * Wn + w;
    const int r1 = (int)(ridx[w] & 0xffffu);
    const float* kbase = kern_lds + r1 * 12;

    float nb[9];                           // 1-channel-ahead prefetch
#define LOADT(CI)                                                         \
    do {                                                                  \
        const float* xc = xbase + (16 * q + (CI)) * (Hn * Wn);            \
        nb[0] = okm ? xc[-Wn + wl] : 0.f;                                 \
        nb[1] = okm ? xc[-Wn] : 0.f;                                      \
        nb[2] = okm ? xc[-Wn + wr_] : 0.f;                                \
        nb[3] = xc[wl];                                                   \
        nb[4] = xc[0];                                                    \
        nb[5] = xc[wr_];                                                  \
        nb[6] = okp ? xc[Wn + wl] : 0.f;                                  \
        nb[7] = okp ? xc[Wn] : 0.f;                                       \
        nb[8] = okp ? xc[Wn + wr_] : 0.f;                                 \
    } while (0)

    uint4 pk;
    float tprev = 0.f;
    LOADT(0);
#pragma unroll
    for (int ci = 0; ci < 16; ++ci) {
        float ab[9];
#pragma unroll
        for (int i = 0; i < 9; ++i) ab[i] = nb[i];
        if (ci < 15) LOADT(ci + 1);                // issue next channel's loads

        // mask clamped-border columns (per-lane uniform cndmask)
        float a0 = mL ? ab[0] : 0.f, b0 = mL ? ab[3] : 0.f, c0 = mL ? ab[6] : 0.f;
        float a2 = mR ? ab[2] : 0.f, b2 = mR ? ab[5] : 0.f, c2 = mR ? ab[8] : 0.f;

        const float* kp = kbase + (16 * q + ci) * 48;    // 4-addr multicast
        float4 k03 = *(const float4*)kp;
        float4 k47 = *(const float4*)(kp + 4);
        float k8 = kp[8];
        float t = a0 * k03.x + ab[1] * k03.y + a2 * k03.z
                + b0 * k03.w + ab[4] * k47.x + b2 * k47.y
                + c0 * k47.z + ab[7] * k47.w + c2 * k8;
        t = leaky(t);

        if (ci & 1) {
            unsigned qq = bf16pair(tprev, t);
            const int slot = (ci >> 1) & 3;
            if (slot == 0) pk.x = qq;
            else if (slot == 1) pk.y = qq;
            else if (slot == 2) pk.z = qq;
            else {
                pk.w = qq;                          // 8 channels complete
                *(uint4*)&t_lds[2 * q + (ci >> 3)][w][0] = pk;
            }
        } else {
            tprev = t;
        }
    }
#undef LOADT
    __syncthreads();

    // ---- phase 2: MFMA channel mix + fused epilogue (verified path) ----
    const int lane = tid & 63;
    const int v = tid >> 6;               // wave 0..7
    const int wt = v & 3;                 // w-tile (32 cols)
    const int oh = v >> 2;                // o-half (32 rows)
    const int col = lane & 31;
    const int kh = lane >> 5;
    const int wn = wt * 32 + col;         // this lane's output column

    v8bf Bf[4];
#pragma unroll
    for (int ks = 0; ks < 4; ++ks)
        Bf[ks] = *(const v8bf*)&t_lds[2 * ks + kh][wn][0];

    v16f acc;
#pragma unroll
    for (int i = 0; i < 16; ++i) acc[i] = 0.f;

#pragma unroll
    for (int ks = 0; ks < 4; ++ks) {
        const int cq = 2 * ks + kh;
        v8bf Af = *(const v8bf*)&wc_lds[cq][oh * 32 + col][0];
        acc = __builtin_amdgcn_mfma_f32_32x32x16_bf16(Af, Bf[ks], acc, 0, 0, 0);
    }

    const int r2e = (int)(ridx[wn] >> 16);
    const float* xcol = x0 + ((size_t)(b * Cn + oh * 32) * Hn + h) * Wn + wn;
    float* ocol = out + ((size_t)(b * Cn + oh * 32) * Hn + h) * Wn + wn;

#pragma unroll
    for (int r = 0; r < 16; ++r) {
        int row = (r & 3) + 8 * (r >> 2) + 4 * kh;     // 0..31 within tile
        int o = oh * 32 + row;
        float xv = xcol[(size_t)row * (Hn * Wn)];      // L2 hit
        float res = acc[r] + bias_lds[o] + xv * att_lds[r2e * 68 + o];
        ocol[(size_t)row * (Hn * Wn)] = res;           // 128B coalesced
    }
}

// ---------------------------------------------------------------------------
extern "C" void kernel_launch(void* const* d_in, const int* in_sizes, int n_in,
                              void* d_out, int out_size, void* d_ws, size_t ws_size,
                              hipStream_t stream)
{
    const float* x0     = (const float*)d_in[0];
    const float* deg    = (const float*)d_in[1];
    const float* q_map  = (const float*)d_in[2];
    const float* w_k1   = (const float*)d_in[3];
    const float* w_k2   = (const float*)d_in[4];
    const float* w_conv = (const float*)d_in[5];
    const float* b_conv = (const float*)d_in[6];
    const float* w_ca1  = (const float*)d_in[7];
    const float* w_ca2  = (const float*)d_in[8];
    const float* w_g1   = (const float*)d_in[9];
    const float* b_g1   = (const float*)d_in[10];
    const float* w_g2   = (const float*)d_in[11];
    const float* b_g2   = (const float*)d_in[12];
    float* outp   = (float*)d_out;
    float* kern_g = (float*)d_ws;                           // 8*3072 floats
    float* att_g  = kern_g + Bn * 3072;                     // 8*256 floats
    unsigned short* wbf = (unsigned short*)(att_g + Bn * 256);  // 4096 bf16

    precomp_kernel<<<Bn + 1, 256, 0, stream>>>(deg, w_k1, w_k2, w_ca1, w_ca2,
                                               w_conv, kern_g, att_g, wbf);
    da_main<<<Bn * Hn, 512, 0, stream>>>(x0, q_map, wbf, b_conv,
                                         w_g1, b_g1, w_g2, b_g2,
                                         kern_g, att_g, outp);
}